// Round 6
// baseline (513.052 us; speedup 1.0000x reference)
//
#include <hip/hip_runtime.h>
#include <hip/hip_bf16.h>

typedef short short8v __attribute__((ext_vector_type(8)));
typedef short short4v __attribute__((ext_vector_type(4)));
typedef float f32x4v __attribute__((ext_vector_type(4)));

#define T_LEN 512
#define BATCH 64
#define INDIM 1280
#define HDIM 128
#define G4 512      // 4*H (one direction)
#define NCOLS 1024  // both directions
#define NCLS 263

typedef __attribute__((address_space(1))) const void gvoid_t;
typedef __attribute__((address_space(3))) void lvoid_t;
#define GLOAD_LDS16(g, l) __builtin_amdgcn_global_load_lds((gvoid_t*)(g), (lvoid_t*)(l), 16, 0, 0)

static __device__ __forceinline__ short f2bf(float f) {
    union { float f; unsigned u; } v; v.f = f;
    unsigned r = v.u + 0x7FFF + ((v.u >> 16) & 1);
    return (short)(r >> 16);
}

// ---------------- convert x (fp32) -> bf16 ----------------
__global__ void convert_x_kernel(const float4* __restrict__ x, short4v* __restrict__ out, int n4) {
    int i = blockIdx.x * blockDim.x + threadIdx.x;
    int stride = gridDim.x * blockDim.x;
    for (; i < n4; i += stride) {
        float4 v = x[i];
        short4v o;
        o[0] = f2bf(v.x); o[1] = f2bf(v.y); o[2] = f2bf(v.z); o[3] = f2bf(v.w);
        out[i] = o;
    }
}

// ---------------- convert Wih_f/Wih_b -> bf16 [1024][1280], combine biases ----------------
__global__ void convert_w_kernel(const float* __restrict__ Wf, const float* __restrict__ Wb,
                                 const float* __restrict__ bihf, const float* __restrict__ bhhf,
                                 const float* __restrict__ bihb, const float* __restrict__ bhhb,
                                 short* __restrict__ wout, float* __restrict__ biasc) {
    int i = blockIdx.x * blockDim.x + threadIdx.x;
    int stride = gridDim.x * blockDim.x;
    const int n4 = (G4 * INDIM) / 4;  // 163840 float4 per direction
    for (int k = i; k < 2 * n4; k += stride) {
        const float4* src = (k < n4) ? (const float4*)Wf : (const float4*)Wb;
        float4 v = src[(k < n4) ? k : (k - n4)];
        short4v o;
        o[0] = f2bf(v.x); o[1] = f2bf(v.y); o[2] = f2bf(v.z); o[3] = f2bf(v.w);
        ((short4v*)wout)[k] = o;
    }
    if (i < NCOLS)
        biasc[i] = (i < G4) ? (bihf[i] + bhhf[i]) : (bihb[i - G4] + bhhb[i - G4]);
}

// ---------------- big GEMM: xp[M=32768][1024] = x_bf16[M][1280] * w_bf16[1024][1280]^T + bias ----------------
#define BM 128
#define BN 128
#define BK 32

__global__ __launch_bounds__(256) void gemm_xp_kernel(const short* __restrict__ A,
                                                      const short* __restrict__ Bw,
                                                      const float* __restrict__ bias,
                                                      float* __restrict__ C) {
    __shared__ __align__(16) short As[BM * BK];
    __shared__ __align__(16) short Bs[BN * BK];
    const int tid = threadIdx.x;
    const int w = tid >> 6;
    const int l = tid & 63;
    const int bm = blockIdx.x * BM;
    const int bn = blockIdx.y * BN;
    const int wm = (w >> 1) * 64;
    const int wn = (w & 1) * 64;
    const int lr = l & 15;
    const int lk = (l >> 4) * 8;

    f32x4v acc[4][4];
#pragma unroll
    for (int m = 0; m < 4; m++)
#pragma unroll
        for (int n = 0; n < 4; n++) acc[m][n] = (f32x4v)0.0f;

    const int srow = tid >> 2;        // 0..63
    const int scol = (tid & 3) * 8;   // bf16 k-offset

    // prologue: stage tile k0=0
#pragma unroll
    for (int i = 0; i < 2; i++) {
        GLOAD_LDS16(A + (long)(bm + i * 64 + srow) * INDIM + scol, &As[(i * 64 + (w << 4)) * BK]);
        GLOAD_LDS16(Bw + (long)(bn + i * 64 + srow) * INDIM + scol, &Bs[(i * 64 + (w << 4)) * BK]);
    }

    for (int k0 = 0; k0 < INDIM; k0 += BK) {
        __syncthreads();  // staged data visible
        short8v af[4], bf[4];
#pragma unroll
        for (int m = 0; m < 4; m++) af[m] = *(const short8v*)&As[(wm + m * 16 + lr) * BK + lk];
#pragma unroll
        for (int n = 0; n < 4; n++) bf[n] = *(const short8v*)&Bs[(wn + n * 16 + lr) * BK + lk];
        __syncthreads();  // all waves done reading LDS
        if (k0 + BK < INDIM) {
            const int k1 = k0 + BK;
#pragma unroll
            for (int i = 0; i < 2; i++) {
                GLOAD_LDS16(A + (long)(bm + i * 64 + srow) * INDIM + k1 + scol, &As[(i * 64 + (w << 4)) * BK]);
                GLOAD_LDS16(Bw + (long)(bn + i * 64 + srow) * INDIM + k1 + scol, &Bs[(i * 64 + (w << 4)) * BK]);
            }
        }
#pragma unroll
        for (int m = 0; m < 4; m++)
#pragma unroll
            for (int n = 0; n < 4; n++)
                acc[m][n] = __builtin_amdgcn_mfma_f32_16x16x32_bf16(af[m], bf[n], acc[m][n], 0, 0, 0);
    }

    // epilogue: add bias, store fp32
#pragma unroll
    for (int m = 0; m < 4; m++) {
        const int row = bm + wm + m * 16 + (l >> 4) * 4;
#pragma unroll
        for (int n = 0; n < 4; n++) {
            const int col = bn + wn + n * 16 + lr;
            const float bv = bias[col];
#pragma unroll
            for (int r = 0; r < 4; r++)
                C[(long)(row + r) * NCOLS + col] = acc[m][n][r] + bv;
        }
    }
}

// ---------------- recurrence: 64 blocks = 32 batch-groups (2 batches) x 2 directions ----------------
// 256 threads = 4 waves (1/SIMD). Wave w owns hidden cols [32w,32w+32) x ALL 4 gates:
// tile nt -> gate (nt&3), col-half (nt>>2); Whh rows (nt&3)*128 + w*32 + (nt>>2)*16 + lr.
// MFMA chains interleaved kk-outer/nt-inner (8 independent accumulators) so back-to-back
// MFMAs never depend on each other. Gate redistribution is WAVE-LOCAL through gw[w]
// (in-order DS pipe per wave, no barrier). Only h crosses waves -> ONE barrier per step
// (lgkm-only, no vmcnt drain). xp prefetched 2 steps ahead.
__global__ __launch_bounds__(256, 1) void lstm_rec_kernel(const float* __restrict__ xp,
                                                          const float* __restrict__ Whh_f,
                                                          const float* __restrict__ Whh_b,
                                                          float* __restrict__ pooled) {
    __shared__ __align__(16) short hbf[2][3][136];    // rows 0,1 = batches; row 2 = zeros
    __shared__ __align__(16) float gw[4][4][2][32];   // [wave][gate][batch][col-in-wave]

    const int bid = blockIdx.x;  // 0..63
    const int d = bid & 1;
    const int b0 = (bid >> 1) * 2;   // 2 batches per block
    const int tid = threadIdx.x;
    const int w = tid >> 6;      // wave 0..3
    const int l = tid & 63;
    const int lr = l & 15;       // MFMA A-row lane / output col (batch)
    const int lg = l >> 4;       // 0..3
    const int lk = lg * 8;
    const int hrow = lr < 2 ? lr : 2;  // broadcast zero row for invalid batches

    const float* __restrict__ Whh = d ? Whh_b : Whh_f;

    // Preload Whh as MFMA A-fragments (time-invariant), gate-interleaved per wave:
    // afragW[nt][kk] = bf16(Whh[(nt&3)*128 + w*32 + (nt>>2)*16 + lr][kk*32 + lk .. +8])
    short8v afragW[8][4];
#pragma unroll
    for (int nt = 0; nt < 8; nt++) {
        const int gc = (nt & 3) * 128 + w * 32 + (nt >> 2) * 16 + lr;
#pragma unroll
        for (int kk = 0; kk < 4; kk++) {
            const float* src = Whh + gc * HDIM + kk * 32 + lk;
            short8v f;
#pragma unroll
            for (int j = 0; j < 8; j++) f[j] = f2bf(src[j]);
            afragW[nt][kk] = f;
        }
    }

    // zero both h buffers (row 2 must stay zero forever)
    for (int i = tid; i < 2 * 3 * 136; i += 256) ((short*)hbf)[i] = 0;

    // elementwise ownership: one element per lane, within this wave's 32 cols
    const int eb = l >> 5;           // batch 0..1
    const int ecl = l & 31;          // col within wave
    const int ec = w * 32 + ecl;     // hidden col 0..127
    const float* xbase = xp + (long)(b0 + eb) * T_LEN * NCOLS + d * G4 + ec;

    float c = 0.0f;
    float hmax = -1e30f;
    const f32x4v z4 = (f32x4v)0.0f;  // persistent zero C-operand

#define LOADXV(tq, dst) { \
    int tt_ = d ? (T_LEN - 1 - (tq)) : (tq); \
    tt_ = tt_ < 0 ? 0 : (tt_ > T_LEN - 1 ? T_LEN - 1 : tt_); \
    const float* p_ = xbase + (long)tt_ * NCOLS; \
    _Pragma("unroll") for (int nt_ = 0; nt_ < 4; nt_++) \
        dst[nt_] = p_[nt_ * 128]; \
}

    float xvA[4], xvB[4];
    LOADXV(0, xvA);
    LOADXV(1, xvB);

    __syncthreads();

#define L2E 1.44269504088896f

#define STEP(t, pb, xv) { \
    short8v hfrag[4]; \
    _Pragma("unroll") for (int kk = 0; kk < 4; kk++) \
        hfrag[kk] = *(const short8v*)&hbf[pb][hrow][kk * 32 + lk]; \
    f32x4v acc[8]; \
    _Pragma("unroll") for (int nt = 0; nt < 8; nt++) \
        acc[nt] = __builtin_amdgcn_mfma_f32_16x16x32_bf16(afragW[nt][0], hfrag[0], z4, 0, 0, 0); \
    _Pragma("unroll") for (int kk = 1; kk < 4; kk++) \
        _Pragma("unroll") for (int nt = 0; nt < 8; nt++) \
            acc[nt] = __builtin_amdgcn_mfma_f32_16x16x32_bf16(afragW[nt][kk], hfrag[kk], acc[nt], 0, 0, 0); \
    if (lr < 2) { \
        _Pragma("unroll") for (int nt = 0; nt < 8; nt++) \
            *(f32x4v*)&gw[w][nt & 3][lr][(nt >> 2) * 16 + lg * 4] = acc[nt]; \
    } \
    { \
        float gi = gw[w][0][eb][ecl] + xv[0]; \
        float gf = gw[w][1][eb][ecl] + xv[1]; \
        float gg = gw[w][2][eb][ecl] + xv[2]; \
        float go = gw[w][3][eb][ecl] + xv[3]; \
        float ea = __builtin_amdgcn_exp2f(-gi * L2E); \
        float eb_ = __builtin_amdgcn_exp2f(-gf * L2E); \
        float pa = 1.0f + ea, pbv = 1.0f + eb_; \
        float inv1 = __builtin_amdgcn_rcpf(pa * pbv); \
        float si = pbv * inv1; \
        float sf = pa * inv1; \
        float eg = __builtin_amdgcn_exp2f(gg * (2.0f * L2E)); \
        float eo = __builtin_amdgcn_exp2f(-go * L2E); \
        float pg = 1.0f + eg, po = 1.0f + eo; \
        float inv2 = __builtin_amdgcn_rcpf(pg * po); \
        float tg = 1.0f - 2.0f * po * inv2; \
        float so = pg * inv2; \
        c = sf * c + si * tg; \
        float ecx = __builtin_amdgcn_exp2f(c * (2.0f * L2E)); \
        float tc = 1.0f - 2.0f * __builtin_amdgcn_rcpf(1.0f + ecx); \
        float h = so * tc; \
        hmax = fmaxf(hmax, h); \
        hbf[(pb) ^ 1][eb][ec] = f2bf(h); \
    } \
    LOADXV((t) + 2, xv); \
    asm volatile("s_waitcnt lgkmcnt(0)\n\ts_barrier" ::: "memory"); \
}

    for (int t = 0; t < T_LEN; t += 2) {
        STEP(t, 0, xvA);
        STEP(t + 1, 1, xvB);
    }

    pooled[(b0 + eb) * 256 + d * 128 + ec] = hmax;
#undef STEP
#undef LOADXV
}

// ---------------- head: out[64][263] = pooled[64][256] @ W1^T + b1 ----------------
__global__ void logits_kernel(const float* __restrict__ pooled, const float* __restrict__ W1,
                              const float* __restrict__ b1, float* __restrict__ out) {
    __shared__ float p[256];
    const int b = blockIdx.x;
    const int n = threadIdx.x;
    if (n < 256) p[n] = pooled[b * 256 + n];
    __syncthreads();
    if (n < NCLS) {
        float s = b1[n];
        const float* wr = W1 + n * 256;
#pragma unroll 8
        for (int k = 0; k < 256; k++) s += p[k] * wr[k];
        out[b * NCLS + n] = s;
    }
}

extern "C" void kernel_launch(void* const* d_in, const int* in_sizes, int n_in,
                              void* d_out, int out_size, void* d_ws, size_t ws_size,
                              hipStream_t stream) {
    (void)in_sizes; (void)n_in; (void)out_size; (void)ws_size;
    const float* x     = (const float*)d_in[0];
    const float* Wih_f = (const float*)d_in[1];
    const float* Whh_f = (const float*)d_in[2];
    const float* bih_f = (const float*)d_in[3];
    const float* bhh_f = (const float*)d_in[4];
    const float* Wih_b = (const float*)d_in[5];
    const float* Whh_b = (const float*)d_in[6];
    const float* bih_b = (const float*)d_in[7];
    const float* bhh_b = (const float*)d_in[8];
    const float* W1    = (const float*)d_in[9];
    const float* b1    = (const float*)d_in[10];
    float* out = (float*)d_out;

    char* ws = (char*)d_ws;
    short* x_bf   = (short*)ws;                    // 32768*1280*2  = 83,886,080
    short* w_bf   = (short*)(ws + 83886080);       // 1024*1280*2   =  2,621,440
    float* biasc  = (float*)(ws + 86507520);       // 1024*4        =      4,096
    float* xp     = (float*)(ws + 86511616);       // 32768*1024*4  = 134,217,728
    float* pooled = (float*)(ws + 220729344);      // 64*256*4      =     65,536

    convert_x_kernel<<<2048, 256, 0, stream>>>((const float4*)x, (short4v*)x_bf, (T_LEN * BATCH * INDIM) / 4);
    convert_w_kernel<<<512, 256, 0, stream>>>(Wih_f, Wih_b, bih_f, bhh_f, bih_b, bhh_b, w_bf, biasc);
    dim3 g(BATCH * T_LEN / BM, NCOLS / BN);  // (256, 8)
    gemm_xp_kernel<<<g, 256, 0, stream>>>(x_bf, w_bf, biasc, xp);
    lstm_rec_kernel<<<64, 256, 0, stream>>>(xp, Whh_f, Whh_b, pooled);
    logits_kernel<<<64, 320, 0, stream>>>(pooled, W1, b1, out);
}